// Round 12
// baseline (173.262 us; speedup 1.0000x reference)
//
#include <hip/hip_runtime.h>

typedef unsigned short ushort_t;
typedef _Float16 half_t;
typedef __attribute__((ext_vector_type(2))) _Float16 half2_t;
typedef __attribute__((ext_vector_type(8))) _Float16 half8_t;
typedef __attribute__((ext_vector_type(2))) __fp16 fp16x2;
typedef __attribute__((ext_vector_type(2))) float fx2;
typedef __attribute__((ext_vector_type(4))) float floatx4;

#define LOG2E 1.4426950408889634f
#define LN2   0.6931471805599453f

__device__ __forceinline__ float exp2_(float x) {
#if __has_builtin(__builtin_amdgcn_exp2f)
    return __builtin_amdgcn_exp2f(x);
#else
    return exp2f(x);
#endif
}

__device__ __forceinline__ half2_t cvt_pk_f16(float a, float b) {
    auto r = __builtin_amdgcn_cvt_pkrtz(a, b);
    return __builtin_bit_cast(half2_t, r);
}

__device__ __forceinline__ float fdot2_(half2_t a, half2_t b) {
#if __has_builtin(__builtin_amdgcn_fdot2)
    return __builtin_amdgcn_fdot2(__builtin_bit_cast(fp16x2, a),
                                  __builtin_bit_cast(fp16x2, b), 0.0f, false);
#else
    return (float)a.x * (float)b.x + (float)a.y * (float)b.y;
#endif
}

// packed mish in log2-domain: input t0 = x*log2e, output = mish(x)/ln2
__device__ __forceinline__ fx2 mish2(fx2 t0) {
    fx2 one = {1.0f, 1.0f};
    fx2 m2  = {-2.0f, -2.0f};
    fx2 u   = {exp2_(t0.x), exp2_(t0.y)};
    fx2 s   = u + one;
    fx2 wv  = __builtin_elementwise_fma(s, s, one);     // e^2x+2e^x+2
    fx2 rr  = {__builtin_amdgcn_rcpf(wv.x), __builtin_amdgcn_rcpf(wv.y)};
    fx2 v   = __builtin_elementwise_fma(rr, m2, one);   // tanh(softplus)
    return t0 * v;
}

// sum across each 16-lane row, pure VALU (DPP), no LDS
__device__ __forceinline__ float dpp_sum16(float v) {
    int x = __float_as_int(v);
    v += __int_as_float(__builtin_amdgcn_update_dpp(0, x, 0xB1, 0xF, 0xF, true));
    x = __float_as_int(v);
    v += __int_as_float(__builtin_amdgcn_update_dpp(0, x, 0x4E, 0xF, 0xF, true));
    x = __float_as_int(v);
    v += __int_as_float(__builtin_amdgcn_update_dpp(0, x, 0x124, 0xF, 0xF, true));
    x = __float_as_int(v);
    v += __int_as_float(__builtin_amdgcn_update_dpp(0, x, 0x128, 0xF, 0xF, true));
    return v;
}

// ---------------- prep (unchanged from R10/R11) ----------------
__global__ __launch_bounds__(256) void prep_kernel(
        const float* __restrict__ state,
        const float* __restrict__ action,
        const float* __restrict__ W1,
        const float* __restrict__ b1,
        const float* __restrict__ W2,
        float* __restrict__ obsW,
        half_t* __restrict__ actW,
        half_t* __restrict__ W2T,
        float* __restrict__ out) {
    int bid = blockIdx.x;
    int t = threadIdx.x;
    if (bid < 512) {
        int b = bid;
        const float* stp = state + (size_t)b * 512;
        const float* w1p = W1 + t;
        float a0 = 0.f, a1 = 0.f, a2 = 0.f, a3 = 0.f;
#pragma unroll 8
        for (int f = 0; f < 512; f += 4) {
            a0 = fmaf(stp[f + 0], w1p[(f + 0) * 256], a0);
            a1 = fmaf(stp[f + 1], w1p[(f + 1) * 256], a1);
            a2 = fmaf(stp[f + 2], w1p[(f + 2) * 256], a2);
            a3 = fmaf(stp[f + 3], w1p[(f + 3) * 256], a3);
        }
        obsW[b * 256 + t] = ((a0 + a1) + (a2 + a3) + b1[t]) * LOG2E;
    } else if (bid < 2560) {
        int idx = bid - 512;
        int j = idx & 7;
        int b0 = (idx >> 3) * 2;
        const float* W1a = W1 + (size_t)(512 + j * 16) * 256;
        float wv[16];
#pragma unroll
        for (int a = 0; a < 16; ++a) wv[a] = W1a[a * 256 + t];
#pragma unroll
        for (int bb = 0; bb < 2; ++bb) {
            int b = b0 + bb;
            const float* acp = action + (size_t)b * 128;
            float acc[8];
#pragma unroll
            for (int n = 0; n < 8; ++n) acc[n] = 0.f;
#pragma unroll
            for (int a = 0; a < 16; ++a) {
#pragma unroll
                for (int n = 0; n < 8; ++n)
                    acc[n] = fmaf(acp[n * 16 + a], wv[a], acc[n]);
            }
#pragma unroll
            for (int n = 0; n < 8; ++n)
                actW[(((size_t)b * 8 + n) * 8 + j) * 256 + t] = (half_t)(acc[n] * LOG2E);
        }
    } else {
        int blk = bid - 2560;
        if (blk < 16) {
            out[blk * 512 + t] = 0.0f;
            out[blk * 512 + 256 + t] = 0.0f;
        }
        int n = blk * 8 + (t >> 5);
        int klo = t & 31;
#pragma unroll
        for (int kk = 0; kk < 8; ++kk) {
            int k = kk * 32 + klo;
            W2T[n * 256 + k] = (half_t)W2[k * 256 + n];
        }
    }
}

// ---------------- main: four s-groups per block, 3-deep software pipeline ----------------
#define CHUNK_US 528

__global__ __launch_bounds__(512, 4) void main_kernel(
        const float* __restrict__ obsW, const half_t* __restrict__ actW,
        const half_t* __restrict__ W2T, const int* __restrict__ perm,
        const float* __restrict__ b2,
        const float* __restrict__ W3, const float* __restrict__ b3,
        float* __restrict__ out) {
    __shared__ __align__(16) ushort_t h1[2][32 * CHUNK_US];  // 66 KB ping-pong
    __shared__ __align__(16) float obsb[256];
    __shared__ int perm_s[256];                              // 32 s x 8
    __shared__ float qpart[4][8][64];                        // 8 KB

    int t = threadIdx.x;
    int bid = blockIdx.x;
    int b = (bid & 7) * 64 + ((bid >> 3) & 63);   // XCD swizzle; 2 blocks per b
    int s0 = (bid >> 9) * 32;                     // half 0/1

    int w = t >> 6;
    int L = t & 63;
    int lo = L & 15;
    int q = L >> 4;

    if (t < 256) obsb[t] = obsW[b * 256 + t];
    else perm_s[t - 256] = perm[((size_t)b * 64 + s0) * 8 + (t - 256)];

    const half_t* w2base = W2T + ((size_t)(w * 32 + lo)) * 256 + q * 8;

    // build geometry: thread covers cols L*4..L*4+3 of rows (w*8+j)
    int g2 = L >> 1;
    int ksg = g2 >> 2;
    int qq = g2 & 3;
    int halfsel = L & 1;
    const half_t* actg = actW + (size_t)b * 64 * 256 + L * 4;
    int dstoff = qq * 128 + halfsel * 4 + ksg * CHUNK_US;

    int col0 = w * 32 + 0 * 16 + lo;
    int col1 = w * 32 + 1 * 16 + lo;
    fx2 b2p = {b2[col0] * LOG2E, b2[col1] * LOG2E};
    half2_t w3p = cvt_pk_f16(W3[col0] * LN2, W3[col1] * LN2);

    __syncthreads();   // obsb/perm_s visible

    float4 ob = *reinterpret_cast<const float4*>(obsb + L * 4);

    // ---- build group 0 into h1[0] ----
    {
        uint2 av[8];
#pragma unroll
        for (int j = 0; j < 8; ++j) {
            int p = perm_s[w * 8 + j];
            av[j] = *reinterpret_cast<const uint2*>(actg + (p * 8 + j) * 256);
        }
        fx2 r01 = {ob.x, ob.y};
        fx2 r23 = {ob.z, ob.w};
        ushort_t* dst = h1[0] + dstoff;
#pragma unroll
        for (int j = 0; j < 8; ++j) {
            half2_t a0 = __builtin_bit_cast(half2_t, av[j].x);
            half2_t a1 = __builtin_bit_cast(half2_t, av[j].y);
            r01 += (fx2){(float)a0.x, (float)a0.y};
            r23 += (fx2){(float)a1.x, (float)a1.y};
            fx2 h01 = mish2(r01);
            fx2 h23 = mish2(r23);
            int row = w * 8 + j;
            int mt2 = row >> 4, lr = row & 15;
            uint2 pk = make_uint2(__builtin_bit_cast(unsigned, cvt_pk_f16(h01.x, h01.y)),
                                  __builtin_bit_cast(unsigned, cvt_pk_f16(h23.x, h23.y)));
            *reinterpret_cast<uint2*>(dst + mt2 * 8 * CHUNK_US + lr * 8) = pk;
        }
    }
    __syncthreads();   // h1[0] ready

    floatx4 acc[2][4][2];

#pragma unroll
    for (int g = 0; g < 4; ++g) {
        int cur = g & 1;
        int nxt = cur ^ 1;
#pragma unroll
        for (int mt = 0; mt < 4; ++mt)
#pragma unroll
            for (int nt = 0; nt < 2; ++nt)
                acc[cur][mt][nt] = (floatx4){0.f, 0.f, 0.f, 0.f};

        uint2 av[8];
        fx2 r01, r23;
        if (g < 3) {
#pragma unroll
            for (int j = 0; j < 8; ++j) {
                int p = perm_s[(g + 1) * 64 + w * 8 + j];
                av[j] = *reinterpret_cast<const uint2*>(actg + (p * 8 + j) * 256);
            }
            r01 = (fx2){ob.x, ob.y};
            r23 = (fx2){ob.z, ob.w};
        }
        const ushort_t* h1b = h1[cur] + L * 8;
        ushort_t* dst = h1[nxt] + dstoff;

#pragma unroll
        for (int ks = 0; ks < 8; ++ks) {
            half8_t afr[4];
#pragma unroll
            for (int mt = 0; mt < 4; ++mt)
                afr[mt] = *reinterpret_cast<const half8_t*>(h1b + (mt * 8 + ks) * CHUNK_US);
            half8_t bfr0 = *reinterpret_cast<const half8_t*>(w2base + 0 * 4096 + ks * 32);
            half8_t bfr1 = *reinterpret_cast<const half8_t*>(w2base + 1 * 4096 + ks * 32);
#pragma unroll
            for (int mt = 0; mt < 4; ++mt) {
                acc[cur][mt][0] = __builtin_amdgcn_mfma_f32_16x16x32_f16(afr[mt], bfr0, acc[cur][mt][0], 0, 0, 0);
                acc[cur][mt][1] = __builtin_amdgcn_mfma_f32_16x16x32_f16(afr[mt], bfr1, acc[cur][mt][1], 0, 0, 0);
            }
            if (g < 3) {   // build step j=ks of group g+1 (fills MFMA shadow)
                half2_t a0 = __builtin_bit_cast(half2_t, av[ks].x);
                half2_t a1 = __builtin_bit_cast(half2_t, av[ks].y);
                r01 += (fx2){(float)a0.x, (float)a0.y};
                r23 += (fx2){(float)a1.x, (float)a1.y};
                fx2 h01 = mish2(r01);
                fx2 h23 = mish2(r23);
                int row = w * 8 + ks;
                int mt2 = row >> 4, lr = row & 15;
                uint2 pk = make_uint2(__builtin_bit_cast(unsigned, cvt_pk_f16(h01.x, h01.y)),
                                      __builtin_bit_cast(unsigned, cvt_pk_f16(h23.x, h23.y)));
                *reinterpret_cast<uint2*>(dst + mt2 * 8 * CHUNK_US + lr * 8) = pk;
            }
            if (g > 0) {   // epilogue of group g-1: 2 of 16 (mt,r) per ks
                int prv = cur ^ 1;
#pragma unroll
                for (int v = 0; v < 2; ++v) {
                    int idx = ks * 2 + v;
                    int mt = idx >> 2, r = idx & 3;
                    fx2 t2 = {acc[prv][mt][0][r], acc[prv][mt][1][r]};
                    t2 += b2p;
                    fx2 hh = mish2(t2);
                    float part = fdot2_(cvt_pk_f16(hh.x, hh.y), w3p);
                    float s = dpp_sum16(part);
                    if (lo == 0) qpart[g - 1][w][mt * 16 + q * 4 + r] = s;
                }
            }
        }
        __syncthreads();
    }

    // ---- epilogue of group 3 (acc[1]) ----
#pragma unroll
    for (int idx = 0; idx < 16; ++idx) {
        int mt = idx >> 2, r = idx & 3;
        fx2 t2 = {acc[1][mt][0][r], acc[1][mt][1][r]};
        t2 += b2p;
        fx2 hh = mish2(t2);
        float part = fdot2_(cvt_pk_f16(hh.x, hh.y), w3p);
        float s = dpp_sum16(part);
        if (lo == 0) qpart[3][w][mt * 16 + q * 4 + r] = s;
    }
    __syncthreads();

    // ---- final: reduce 8 waves, perm-gather, atomic ----
    if (t < 32) {
        int h = t >> 3, i = t & 7;
        float p = 0.f;
#pragma unroll
        for (int sl = 0; sl < 8; ++sl) {
            int k = perm_s[(h * 8 + sl) * 8 + i];
            int row = sl * 8 + k;
            float qv = b3[0];
#pragma unroll
            for (int ww = 0; ww < 8; ++ww) qv += qpart[h][ww][row];
            p += qv;
        }
        p *= (1.0f / 64.0f);
        atomicAdd(&out[b * 8 + i], p);
        atomicAdd(&out[4096 + b * 8 + i], p);
    }
}

extern "C" void kernel_launch(void* const* d_in, const int* in_sizes, int n_in,
                              void* d_out, int out_size, void* d_ws, size_t ws_size,
                              hipStream_t stream) {
    const float* state  = (const float*)d_in[0];
    const float* action = (const float*)d_in[1];
    const float* W1     = (const float*)d_in[2];
    const float* b1     = (const float*)d_in[3];
    const float* W2     = (const float*)d_in[4];
    const float* b2     = (const float*)d_in[5];
    const float* W3     = (const float*)d_in[6];
    const float* b3     = (const float*)d_in[7];
    const int*   perm   = (const int*)d_in[8];
    float* out = (float*)d_out;

    char* ws = (char*)d_ws;
    float*  obsW = (float*)ws;                          // 0.5 MB
    half_t* actW = (half_t*)(ws + 524288);              // 16 MB
    half_t* W2T  = (half_t*)(ws + 524288 + 16777216);   // 128 KB

    prep_kernel<<<2592, 256, 0, stream>>>(state, action, W1, b1, W2, obsW, actW, W2T, out);
    main_kernel<<<1024, 512, 0, stream>>>(obsW, actW, W2T, perm, b2, W3, b3, out);
}

// Round 13
// 163.514 us; speedup vs baseline: 1.0596x; 1.0596x over previous
//
#include <hip/hip_runtime.h>

typedef unsigned short ushort_t;
typedef _Float16 half_t;
typedef __attribute__((ext_vector_type(2))) _Float16 half2_t;
typedef __attribute__((ext_vector_type(8))) _Float16 half8_t;
typedef __attribute__((ext_vector_type(2))) __fp16 fp16x2;
typedef __attribute__((ext_vector_type(2))) float fx2;
typedef __attribute__((ext_vector_type(4))) float floatx4;

#define LOG2E 1.4426950408889634f
#define LN2   0.6931471805599453f

__device__ __forceinline__ float exp2_(float x) {
#if __has_builtin(__builtin_amdgcn_exp2f)
    return __builtin_amdgcn_exp2f(x);
#else
    return exp2f(x);
#endif
}

__device__ __forceinline__ half2_t cvt_pk_f16(float a, float b) {
    auto r = __builtin_amdgcn_cvt_pkrtz(a, b);
    return __builtin_bit_cast(half2_t, r);
}

__device__ __forceinline__ float fdot2_(half2_t a, half2_t b) {
#if __has_builtin(__builtin_amdgcn_fdot2)
    return __builtin_amdgcn_fdot2(__builtin_bit_cast(fp16x2, a),
                                  __builtin_bit_cast(fp16x2, b), 0.0f, false);
#else
    return (float)a.x * (float)b.x + (float)a.y * (float)b.y;
#endif
}

// packed mish in log2-domain: input t0 = x*log2e, output = mish(x)/ln2
__device__ __forceinline__ fx2 mish2(fx2 t0) {
    fx2 one = {1.0f, 1.0f};
    fx2 m2  = {-2.0f, -2.0f};
    fx2 u   = {exp2_(t0.x), exp2_(t0.y)};
    fx2 s   = u + one;
    fx2 wv  = __builtin_elementwise_fma(s, s, one);     // e^2x+2e^x+2
    fx2 rr  = {__builtin_amdgcn_rcpf(wv.x), __builtin_amdgcn_rcpf(wv.y)};
    fx2 v   = __builtin_elementwise_fma(rr, m2, one);   // tanh(softplus)
    return t0 * v;
}

// sum across each 16-lane row, pure VALU (DPP), no LDS
__device__ __forceinline__ float dpp_sum16(float v) {
    int x = __float_as_int(v);
    v += __int_as_float(__builtin_amdgcn_update_dpp(0, x, 0xB1, 0xF, 0xF, true));
    x = __float_as_int(v);
    v += __int_as_float(__builtin_amdgcn_update_dpp(0, x, 0x4E, 0xF, 0xF, true));
    x = __float_as_int(v);
    v += __int_as_float(__builtin_amdgcn_update_dpp(0, x, 0x124, 0xF, 0xF, true));
    x = __float_as_int(v);
    v += __int_as_float(__builtin_amdgcn_update_dpp(0, x, 0x128, 0xF, 0xF, true));
    return v;
}

// ---------------- prep ----------------
// blocks [0,512):      obsW partials: bg=bid>>3 (8 b's), kc=bid&7 (K-chunk of 64)
//                      obsWp[kc][b][t] = sum_{f in chunk} state[b][f]*W1[f][t]
// blocks [512,1536):   actW f16 = (action@W1act)*log2e: idx=bid-512, j=idx&7, b0=(idx>>3)*4
// blocks [1536,1568):  W2T f16 transpose; first 16 also zero `out`
__global__ __launch_bounds__(256) void prep_kernel(
        const float* __restrict__ state,
        const float* __restrict__ action,
        const float* __restrict__ W1,
        const float* __restrict__ W2,
        float* __restrict__ obsWp,
        half_t* __restrict__ actW,
        half_t* __restrict__ W2T,
        float* __restrict__ out) {
    int bid = blockIdx.x;
    int t = threadIdx.x;
    if (bid < 512) {
        int bg = bid >> 3;          // 0..63 -> b = bg*8 .. bg*8+7
        int kc = bid & 7;           // K-chunk, 64 wide
        int bs = bg * 8;
        const float* w1p = W1 + (size_t)(kc * 64) * 256 + t;
        const float* stp = state + (size_t)bs * 512 + kc * 64;  // wave-uniform -> s_load
        float acc[8];
#pragma unroll
        for (int bb = 0; bb < 8; ++bb) acc[bb] = 0.f;
#pragma unroll 4
        for (int f = 0; f < 64; ++f) {
            float w = w1p[f * 256];
#pragma unroll
            for (int bb = 0; bb < 8; ++bb)
                acc[bb] = fmaf(stp[bb * 512 + f], w, acc[bb]);
        }
#pragma unroll
        for (int bb = 0; bb < 8; ++bb)
            obsWp[(size_t)kc * 131072 + (bs + bb) * 256 + t] = acc[bb];
    } else if (bid < 1536) {
        int idx = bid - 512;
        int j = idx & 7;
        int b0 = (idx >> 3) * 4;
        const float* W1a = W1 + (size_t)(512 + j * 16) * 256;
        float wv[16];
#pragma unroll
        for (int a = 0; a < 16; ++a) wv[a] = W1a[a * 256 + t];
#pragma unroll
        for (int bb = 0; bb < 4; ++bb) {
            int b = b0 + bb;
            const float* acp = action + (size_t)b * 128;   // wave-uniform -> s_load
            float acc[8];
#pragma unroll
            for (int n = 0; n < 8; ++n) acc[n] = 0.f;
#pragma unroll
            for (int a = 0; a < 16; ++a) {
#pragma unroll
                for (int n = 0; n < 8; ++n)
                    acc[n] = fmaf(acp[n * 16 + a], wv[a], acc[n]);
            }
#pragma unroll
            for (int n = 0; n < 8; ++n)
                actW[(((size_t)b * 8 + n) * 8 + j) * 256 + t] = (half_t)(acc[n] * LOG2E);
        }
    } else {
        int blk = bid - 1536;             // 0..31
        if (blk < 16) {                   // zero both output copies (8192 floats)
            out[blk * 512 + t] = 0.0f;
            out[blk * 512 + 256 + t] = 0.0f;
        }
        int n = blk * 8 + (t >> 5);
        int klo = t & 31;
#pragma unroll
        for (int kk = 0; kk < 8; ++kk) {
            int k = kk * 32 + klo;
            W2T[n * 256 + k] = (half_t)W2[k * 256 + n];
        }
    }
}

// ---------------- main: two s-groups per block, software-pipelined (R11) ----------------
#define CHUNK_US 528

__global__ __launch_bounds__(512, 4) void main_kernel(
        const float* __restrict__ obsWp, const half_t* __restrict__ actW,
        const half_t* __restrict__ W2T, const int* __restrict__ perm,
        const float* __restrict__ b1, const float* __restrict__ b2,
        const float* __restrict__ W3, const float* __restrict__ b3,
        float* __restrict__ out) {
    __shared__ __align__(16) ushort_t h1[2][32 * CHUNK_US];  // 66 KB
    __shared__ __align__(16) float obsb[256];
    __shared__ int perm_s[128];
    __shared__ float qpart[2][8][64];                        // 4 KB

    int t = threadIdx.x;
    int bid = blockIdx.x;
    int b = (bid & 7) * 64 + ((bid >> 3) & 63);   // XCD swizzle
    int sgp = bid >> 9;                            // 0..3
    int s0 = sgp * 16;

    int w = t >> 6;
    int L = t & 63;
    int lo = L & 15;
    int q = L >> 4;

    if (t < 256) {
        float s = b1[t];
#pragma unroll
        for (int c = 0; c < 8; ++c) s += obsWp[(size_t)c * 131072 + b * 256 + t];
        obsb[t] = s * LOG2E;
    } else if (t < 384) {
        perm_s[t - 256] = perm[((size_t)b * 64 + s0) * 8 + (t - 256)];
    }

    const half_t* w2base = W2T + ((size_t)(w * 32 + lo)) * 256 + q * 8;
    half8_t bpre[4];
    bpre[0] = *reinterpret_cast<const half8_t*>(w2base + 0 * 4096 + 0 * 32);
    bpre[1] = *reinterpret_cast<const half8_t*>(w2base + 1 * 4096 + 0 * 32);
    bpre[2] = *reinterpret_cast<const half8_t*>(w2base + 0 * 4096 + 1 * 32);
    bpre[3] = *reinterpret_cast<const half8_t*>(w2base + 1 * 4096 + 1 * 32);

    // build geometry: thread covers cols L*4..L*4+3 of rows (w*8+j)
    int g = L >> 1;
    int ksg = g >> 2;
    int qq = g & 3;
    int halfsel = L & 1;
    const half_t* actg = actW + (size_t)b * 64 * 256 + L * 4;
    int dstoff = qq * 128 + halfsel * 4 + ksg * CHUNK_US;

    __syncthreads();   // B0: obsb/perm_s visible

    float4 ob = *reinterpret_cast<const float4*>(obsb + L * 4);

    // ---- build half 0 ----
    {
        uint2 av[8];
#pragma unroll
        for (int j = 0; j < 8; ++j) {
            int p = perm_s[(0 * 8 + w) * 8 + j];
            av[j] = *reinterpret_cast<const uint2*>(actg + (p * 8 + j) * 256);
        }
        fx2 r01 = {ob.x, ob.y};
        fx2 r23 = {ob.z, ob.w};
        ushort_t* dst0 = h1[0] + dstoff;
#pragma unroll
        for (int j = 0; j < 8; ++j) {
            half2_t a0 = __builtin_bit_cast(half2_t, av[j].x);
            half2_t a1 = __builtin_bit_cast(half2_t, av[j].y);
            r01 += (fx2){(float)a0.x, (float)a0.y};
            r23 += (fx2){(float)a1.x, (float)a1.y};
            fx2 h01 = mish2(r01);
            fx2 h23 = mish2(r23);
            int row = w * 8 + j;
            int mt2 = row >> 4, lr = row & 15;
            uint2 pk = make_uint2(__builtin_bit_cast(unsigned, cvt_pk_f16(h01.x, h01.y)),
                                  __builtin_bit_cast(unsigned, cvt_pk_f16(h23.x, h23.y)));
            *reinterpret_cast<uint2*>(dst0 + mt2 * 8 * CHUNK_US + lr * 8) = pk;
        }
    }
    __syncthreads();   // B1: h1[0] ready

    // ---- phase 1: K-loop(half0) interleaved with build(half1) ----
    floatx4 acc0[4][2];
#pragma unroll
    for (int mt = 0; mt < 4; ++mt)
#pragma unroll
        for (int nt = 0; nt < 2; ++nt) acc0[mt][nt] = (floatx4){0.f, 0.f, 0.f, 0.f};
    {
        uint2 av[8];
#pragma unroll
        for (int j = 0; j < 8; ++j) {
            int p = perm_s[(1 * 8 + w) * 8 + j];
            av[j] = *reinterpret_cast<const uint2*>(actg + (p * 8 + j) * 256);
        }
        fx2 r01 = {ob.x, ob.y};
        fx2 r23 = {ob.z, ob.w};
        ushort_t* dst1 = h1[1] + dstoff;
        const ushort_t* h1b0 = h1[0] + L * 8;
#pragma unroll
        for (int ks = 0; ks < 8; ++ks) {
            half8_t afr[4];
#pragma unroll
            for (int mt = 0; mt < 4; ++mt)
                afr[mt] = *reinterpret_cast<const half8_t*>(h1b0 + (mt * 8 + ks) * CHUNK_US);
            half8_t bfr0 = (ks == 0) ? bpre[0] : (ks == 1) ? bpre[2]
                         : *reinterpret_cast<const half8_t*>(w2base + 0 * 4096 + ks * 32);
            half8_t bfr1 = (ks == 0) ? bpre[1] : (ks == 1) ? bpre[3]
                         : *reinterpret_cast<const half8_t*>(w2base + 1 * 4096 + ks * 32);
#pragma unroll
            for (int mt = 0; mt < 4; ++mt) {
                acc0[mt][0] = __builtin_amdgcn_mfma_f32_16x16x32_f16(afr[mt], bfr0, acc0[mt][0], 0, 0, 0);
                acc0[mt][1] = __builtin_amdgcn_mfma_f32_16x16x32_f16(afr[mt], bfr1, acc0[mt][1], 0, 0, 0);
            }
            // build1 step j=ks (VALU/trans fills MFMA shadow)
            {
                half2_t a0 = __builtin_bit_cast(half2_t, av[ks].x);
                half2_t a1 = __builtin_bit_cast(half2_t, av[ks].y);
                r01 += (fx2){(float)a0.x, (float)a0.y};
                r23 += (fx2){(float)a1.x, (float)a1.y};
                fx2 h01 = mish2(r01);
                fx2 h23 = mish2(r23);
                int row = w * 8 + ks;
                int mt2 = row >> 4, lr = row & 15;
                uint2 pk = make_uint2(__builtin_bit_cast(unsigned, cvt_pk_f16(h01.x, h01.y)),
                                      __builtin_bit_cast(unsigned, cvt_pk_f16(h23.x, h23.y)));
                *reinterpret_cast<uint2*>(dst1 + mt2 * 8 * CHUNK_US + lr * 8) = pk;
            }
        }
    }
    __syncthreads();   // B2: h1[1] ready, h1[0] consumed

    // ---- phase 2: K-loop(half1) interleaved with epilogue(half0) ----
    int col0 = w * 32 + 0 * 16 + lo;
    int col1 = w * 32 + 1 * 16 + lo;
    fx2 b2p = {b2[col0] * LOG2E, b2[col1] * LOG2E};
    half2_t w3p = cvt_pk_f16(W3[col0] * LN2, W3[col1] * LN2);

    floatx4 acc1[4][2];
#pragma unroll
    for (int mt = 0; mt < 4; ++mt)
#pragma unroll
        for (int nt = 0; nt < 2; ++nt) acc1[mt][nt] = (floatx4){0.f, 0.f, 0.f, 0.f};
    {
        const ushort_t* h1b1 = h1[1] + L * 8;
#pragma unroll
        for (int ks = 0; ks < 8; ++ks) {
            half8_t afr[4];
#pragma unroll
            for (int mt = 0; mt < 4; ++mt)
                afr[mt] = *reinterpret_cast<const half8_t*>(h1b1 + (mt * 8 + ks) * CHUNK_US);
            half8_t bfr0 = (ks == 0) ? bpre[0] : (ks == 1) ? bpre[2]
                         : *reinterpret_cast<const half8_t*>(w2base + 0 * 4096 + ks * 32);
            half8_t bfr1 = (ks == 0) ? bpre[1] : (ks == 1) ? bpre[3]
                         : *reinterpret_cast<const half8_t*>(w2base + 1 * 4096 + ks * 32);
#pragma unroll
            for (int mt = 0; mt < 4; ++mt) {
                acc1[mt][0] = __builtin_amdgcn_mfma_f32_16x16x32_f16(afr[mt], bfr0, acc1[mt][0], 0, 0, 0);
                acc1[mt][1] = __builtin_amdgcn_mfma_f32_16x16x32_f16(afr[mt], bfr1, acc1[mt][1], 0, 0, 0);
            }
            // epilogue(half0): 2 of 16 (mt,r) values per ks
#pragma unroll
            for (int v = 0; v < 2; ++v) {
                int idx = ks * 2 + v;
                int mt = idx >> 2, r = idx & 3;
                fx2 t2 = {acc0[mt][0][r], acc0[mt][1][r]};
                t2 += b2p;
                fx2 hh = mish2(t2);
                float part = fdot2_(cvt_pk_f16(hh.x, hh.y), w3p);
                float s = dpp_sum16(part);
                if (lo == 0) qpart[0][w][mt * 16 + q * 4 + r] = s;
            }
        }
    }
    // ---- epilogue(half1): wave-local (acc1 in regs), no barrier needed ----
#pragma unroll
    for (int idx = 0; idx < 16; ++idx) {
        int mt = idx >> 2, r = idx & 3;
        fx2 t2 = {acc1[mt][0][r], acc1[mt][1][r]};
        t2 += b2p;
        fx2 hh = mish2(t2);
        float part = fdot2_(cvt_pk_f16(hh.x, hh.y), w3p);
        float s = dpp_sum16(part);
        if (lo == 0) qpart[1][w][mt * 16 + q * 4 + r] = s;
    }
    __syncthreads();   // B3: all qpart visible

    // ---- final: reduce 8 waves, perm-gather, atomic ----
    if (t < 16) {
        int h = t >> 3, i = t & 7;
        float p = 0.f;
#pragma unroll
        for (int sl = 0; sl < 8; ++sl) {
            int k = perm_s[(h * 8 + sl) * 8 + i];
            int row = sl * 8 + k;
            float qv = b3[0];
#pragma unroll
            for (int ww = 0; ww < 8; ++ww) qv += qpart[h][ww][row];
            p += qv;
        }
        p *= (1.0f / 64.0f);
        atomicAdd(&out[b * 8 + i], p);
        atomicAdd(&out[4096 + b * 8 + i], p);
    }
}

extern "C" void kernel_launch(void* const* d_in, const int* in_sizes, int n_in,
                              void* d_out, int out_size, void* d_ws, size_t ws_size,
                              hipStream_t stream) {
    const float* state  = (const float*)d_in[0];
    const float* action = (const float*)d_in[1];
    const float* W1     = (const float*)d_in[2];
    const float* b1     = (const float*)d_in[3];
    const float* W2     = (const float*)d_in[4];
    const float* b2     = (const float*)d_in[5];
    const float* W3     = (const float*)d_in[6];
    const float* b3     = (const float*)d_in[7];
    const int*   perm   = (const int*)d_in[8];
    float* out = (float*)d_out;

    char* ws = (char*)d_ws;
    float*  obsWp = (float*)ws;                          // 8*512*256*4 = 4 MB
    half_t* actW  = (half_t*)(ws + 4194304);             // 16 MB
    half_t* W2T   = (half_t*)(ws + 4194304 + 16777216);  // 128 KB

    prep_kernel<<<1568, 256, 0, stream>>>(state, action, W1, W2, obsWp, actW, W2T, out);
    main_kernel<<<2048, 512, 0, stream>>>(obsWp, actW, W2T, perm, b1, b2, W3, b3, out);
}